// Round 8
// baseline (18.417 us; speedup 1.0000x reference)
//
#include <hip/hip_runtime.h>

#define BATCH_N 8192
#define NQ 10
#define CD 138      // comb dim = 128 + 10
#define CPAD 140    // padded row stride (16B-aligned rows, banks spread)
#define RT 32       // rows per block -> grid 256 = 1 block/CU

__global__ __launch_bounds__(256) void qlstm_kernel(
    const float* __restrict__ x,  const float* __restrict__ hx, const float* __restrict__ cx,
    const float* __restrict__ Wf, const float* __restrict__ bf,
    const float* __restrict__ Wi, const float* __restrict__ bi,
    const float* __restrict__ Wu, const float* __restrict__ bu,
    const float* __restrict__ Wo, const float* __restrict__ bo,
    float* __restrict__ out)
{
    __shared__ float sComb[RT][CPAD];    // 17.9 KB
    __shared__ float sGate[4][RT][NQ];   // 5.1 KB

    const int tid = threadIdx.x;
    const int r0  = blockIdx.x * RT;

    // ---- prefetch cx into registers (consumed in phase C) ----
    float cx0 = cx[(size_t)r0 * NQ + tid];                  // idx tid   (<320 for all 256)
    float cx1 = (tid < RT * NQ - 256)
              ? cx[(size_t)r0 * NQ + 256 + tid] : 0.f;      // idx 256+tid (64 threads)

    // ---- stage comb tile: x rows (float4, coalesced) + hx (float2) ----
    {
        const float4* x4 = (const float4*)(x + (size_t)r0 * 128);
        #pragma unroll
        for (int it = 0; it < 4; ++it) {                    // 32 rows * 32 float4
            int idx = tid + it * 256;
            float4 v = x4[idx];
            *(float4*)&sComb[idx >> 5][(idx & 31) * 4] = v;
        }
    }
    if (tid < 160) {                                        // 320 floats as 160 float2
        float2 h2 = ((const float2*)(hx + (size_t)r0 * NQ))[tid];
        int f = tid * 2;
        int row = f / NQ;
        int q   = f - row * NQ;                             // q even, never crosses row end
        sComb[row][128 + q]     = h2.x;
        sComb[row][128 + q + 1] = h2.y;
    }
    if (tid < 2 * RT) sComb[tid >> 1][CD + (tid & 1)] = 0.f; // zero pad cols 138,139

    __syncthreads();

    // ---- fused phase A+B: wave = gate, lane = row ----
    // W/bias accesses are wave-uniform -> scalar (s_load) pipe, no LDS, no staging.
    {
        const int w    = __builtin_amdgcn_readfirstlane(tid >> 6);  // 0:f 1:i 2:u 3:o
        const int lane = tid & 63;
        const float* Wg = (w == 0) ? Wf : (w == 1) ? Wi : (w == 2) ? Wu : Wo;
        const float* Bg = (w == 0) ? bf : (w == 1) ? bi : (w == 2) ? bu : bo;

        if (lane < RT) {
            const int r = lane;
            float acc[NQ];
            #pragma unroll
            for (int q = 0; q < NQ; ++q) acc[q] = Bg[q];

            for (int k4 = 0; k4 < CPAD / 4; ++k4) {
                float4 xv = *(const float4*)&sComb[r][k4 * 4];
                #pragma unroll
                for (int q = 0; q < NQ; ++q) {
                    const float* wp = Wg + q * CD + k4 * 4;  // 8B-aligned, wave-uniform
                    float2 wa = *(const float2*)(wp);
                    float2 wb = *(const float2*)(wp + 2);
                    // k4=34 covers k=136..139: W reads cross into row q+1 for
                    // k=138,139, but xv.z/xv.w are the zero-padded comb entries
                    // there => products are 0 => safe.
                    acc[q] = fmaf(xv.x, wa.x, acc[q]);
                    acc[q] = fmaf(xv.y, wa.y, acc[q]);
                    acc[q] = fmaf(xv.z, wb.x, acc[q]);
                    acc[q] = fmaf(xv.w, wb.y, acc[q]);
                }
            }

            // ---- phase B in registers: z_q = prod_{k<=q, k=q mod 2} cos(theta_k) ----
            float z[NQ];
            #pragma unroll
            for (int q = 0; q < NQ; ++q) {
                float c = cosf(acc[q]);
                z[q] = (q < 2) ? c : z[q - 2] * c;
            }
            #pragma unroll
            for (int q = 0; q < NQ; ++q) {
                float zz = z[q];
                float val = (w == 2) ? tanhf(zz) : 1.f / (1.f + expf(-zz));
                sGate[w][r][q] = val;
            }
        }
    }
    __syncthreads();

    // ---- phase C: LSTM combine; cx already in registers; coalesced stores ----
    const float* G = &sGate[0][0][0];
    #pragma unroll
    for (int it = 0; it < 2; ++it) {
        int idx = tid + it * 256;
        if (idx < RT * NQ) {
            float cxv = it ? cx1 : cx0;
            float fv = G[idx];
            float iv = G[idx + RT * NQ];
            float gv = G[idx + 2 * RT * NQ];
            float ov = G[idx + 3 * RT * NQ];
            float cn = fv * cxv + iv * gv;
            float hn = ov * tanhf(cn);
            out[(size_t)r0 * NQ + idx] = hn;                           // h_new
            out[(size_t)BATCH_N * NQ + (size_t)r0 * NQ + idx] = cn;    // c_new
        }
    }
}

extern "C" void kernel_launch(void* const* d_in, const int* in_sizes, int n_in,
                              void* d_out, int out_size, void* d_ws, size_t ws_size,
                              hipStream_t stream) {
    const float* x  = (const float*)d_in[0];
    const float* hx = (const float*)d_in[1];
    const float* cx = (const float*)d_in[2];
    const float* Wf = (const float*)d_in[3];
    const float* bf = (const float*)d_in[4];
    const float* Wi = (const float*)d_in[5];
    const float* bi = (const float*)d_in[6];
    const float* Wu = (const float*)d_in[7];
    const float* bu = (const float*)d_in[8];
    const float* Wo = (const float*)d_in[9];
    const float* bo = (const float*)d_in[10];
    float* out = (float*)d_out;

    dim3 grid(BATCH_N / RT);   // 256 blocks = 1 per CU
    dim3 block(256);
    hipLaunchKernelGGL(qlstm_kernel, grid, block, 0, stream,
                       x, hx, cx, Wf, bf, Wi, bi, Wu, bu, Wo, bo, out);
}